// Round 1
// baseline (172.164 us; speedup 1.0000x reference)
//
#include <hip/hip_runtime.h>
#include <math.h>

#define NROWS 1024
#define IN_DIM 256
#define OUT_DIM 128
#define D_ACT 64
#define NEG_SLOPE 0.01f

// ---------------------------------------------------------------------------
// K1: s_src[n] = h[n,:] . (W_fc^T @ w_src), s_dst[n] = h[n,:] . (W_fc^T @ w_dst)
// One block (256 threads) per row n. Each thread owns one column m of W_fc,
// folds W_attn into it (128-iter loop, W_fc is 128 KiB -> L2 resident), then
// block-reduces h[n,m]*v[m].
// ---------------------------------------------------------------------------
__global__ __launch_bounds__(256) void compute_s_kernel(
    const float* __restrict__ h,
    const float* __restrict__ W_fc,
    const float* __restrict__ W_attn,
    float* __restrict__ s_src,
    float* __restrict__ s_dst) {
  const int n = blockIdx.x;
  const int m = threadIdx.x;  // 0..255

  float v_src = 0.f, v_dst = 0.f;
#pragma unroll 8
  for (int k = 0; k < OUT_DIM; ++k) {
    float w = W_fc[k * IN_DIM + m];
    v_src += w * W_attn[k];
    v_dst += w * W_attn[OUT_DIM + k];
  }
  const float hv = h[n * IN_DIM + m];
  float ps = hv * v_src;
  float pd = hv * v_dst;

  // wave(64)-level reduce
  for (int off = 32; off > 0; off >>= 1) {
    ps += __shfl_down(ps, off, 64);
    pd += __shfl_down(pd, off, 64);
  }
  __shared__ float sm_s[4], sm_d[4];
  const int wave = m >> 6, lane = m & 63;
  if (lane == 0) { sm_s[wave] = ps; sm_d[wave] = pd; }
  __syncthreads();
  if (m == 0) {
    s_src[n] = sm_s[0] + sm_s[1] + sm_s[2] + sm_s[3];
    s_dst[n] = sm_d[0] + sm_d[1] + sm_d[2] + sm_d[3];
  }
}

// ---------------------------------------------------------------------------
// K2: per-row softmax stats over e[i,j] = lrelu(s_dst[i] + s_src[j]).
// One block (256 threads) per row i; each thread handles 4 j's.
// Stores row max and RECIPROCAL of the denom.
// ---------------------------------------------------------------------------
__global__ __launch_bounds__(256) void row_stats_kernel(
    const float* __restrict__ s_src,
    const float* __restrict__ s_dst,
    float* __restrict__ row_max,
    float* __restrict__ row_rdenom) {
  const int i = blockIdx.x;
  const int t = threadIdx.x;
  const float sd = s_dst[i];

  float ev[4];
  float mx = -INFINITY;
#pragma unroll
  for (int r = 0; r < 4; ++r) {
    float e = sd + s_src[t + r * 256];
    e = e > 0.f ? e : NEG_SLOPE * e;
    ev[r] = e;
    mx = fmaxf(mx, e);
  }
  for (int off = 32; off > 0; off >>= 1) mx = fmaxf(mx, __shfl_down(mx, off, 64));

  __shared__ float sm[4];
  __shared__ float s_bcast;
  const int wave = t >> 6, lane = t & 63;
  if (lane == 0) sm[wave] = mx;
  __syncthreads();
  if (t == 0) s_bcast = fmaxf(fmaxf(sm[0], sm[1]), fmaxf(sm[2], sm[3]));
  __syncthreads();
  const float M = s_bcast;

  float sum = 0.f;
#pragma unroll
  for (int r = 0; r < 4; ++r) sum += __expf(ev[r] - M);
  for (int off = 32; off > 0; off >>= 1) sum += __shfl_down(sum, off, 64);

  __shared__ float ss[4];
  if (lane == 0) ss[wave] = sum;
  __syncthreads();
  if (t == 0) {
    row_max[i] = M;
    row_rdenom[i] = 1.0f / (ss[0] + ss[1] + ss[2] + ss[3]);
  }
}

// ---------------------------------------------------------------------------
// K3: streaming blend. One float4 per loop iteration per thread.
// t indexes float4s; pair p = t>>4 (64 f32 = 16 float4 per (i,j) pair).
// alpha recomputed inline from 4-KiB cached arrays (L1/L2 resident).
// ---------------------------------------------------------------------------
__global__ __launch_bounds__(256) void blend_kernel(
    const float4* __restrict__ action,
    const float4* __restrict__ policy,
    const float* __restrict__ s_src,
    const float* __restrict__ s_dst,
    const float* __restrict__ row_max,
    const float* __restrict__ row_rdenom,
    float4* __restrict__ out,
    int total4) {
  int idx = blockIdx.x * blockDim.x + threadIdx.x;
  const int stride = gridDim.x * blockDim.x;
  for (int t = idx; t < total4; t += stride) {
    const int p = t >> 4;       // (i,j) pair index
    const int i = p >> 10;
    const int j = p & 1023;
    float e = s_dst[i] + s_src[j];
    e = e > 0.f ? e : NEG_SLOPE * e;
    const float alpha = __expf(e - row_max[i]) * row_rdenom[i];
    const float4 a = action[t];
    const float4 q = policy[t];
    float4 o;
    o.x = alpha * a.x + (1.f - alpha) * q.x;
    o.y = alpha * a.y + (1.f - alpha) * q.y;
    o.z = alpha * a.z + (1.f - alpha) * q.z;
    o.w = alpha * a.w + (1.f - alpha) * q.w;
    out[t] = o;
  }
}

extern "C" void kernel_launch(void* const* d_in, const int* in_sizes, int n_in,
                              void* d_out, int out_size, void* d_ws, size_t ws_size,
                              hipStream_t stream) {
  const float* h      = (const float*)d_in[0];
  const float* action = (const float*)d_in[1];
  const float* policy = (const float*)d_in[2];
  const float* W_fc   = (const float*)d_in[3];
  const float* W_attn = (const float*)d_in[4];
  float* out = (float*)d_out;

  // workspace layout: [s_src(1024) | s_dst(1024) | row_max(1024) | row_rdenom(1024)]
  float* s_src      = (float*)d_ws;
  float* s_dst      = s_src + NROWS;
  float* row_max    = s_dst + NROWS;
  float* row_rdenom = row_max + NROWS;

  compute_s_kernel<<<NROWS, 256, 0, stream>>>(h, W_fc, W_attn, s_src, s_dst);
  row_stats_kernel<<<NROWS, 256, 0, stream>>>(s_src, s_dst, row_max, row_rdenom);

  const int total4 = NROWS * NROWS * (D_ACT / 4);  // 16,777,216
  const int nblocks = 8192;
  blend_kernel<<<nblocks, 256, 0, stream>>>(
      (const float4*)action, (const float4*)policy,
      s_src, s_dst, row_max, row_rdenom,
      (float4*)out, total4);
}

// Round 2
// 162.936 us; speedup vs baseline: 1.0566x; 1.0566x over previous
//
#include <hip/hip_runtime.h>
#include <math.h>

#define NROWS 1024
#define IN_DIM 256
#define OUT_DIM 128
#define D_ACT 64
#define NEG_SLOPE 0.01f

// float4s per row of the (i, j, :) tensor: 1024 pairs * 64 floats / 4
#define ROW_T4 (NROWS * D_ACT / 4)      // 16384
#define SEGS_PER_ROW 8
#define SEG_T4 (ROW_T4 / SEGS_PER_ROW)  // 2048 float4s per block
#define SEG_PAIRS (NROWS / SEGS_PER_ROW)  // 128 pairs per block
#define ITERS (SEG_T4 / 256)            // 8 iterations per thread

// ---------------------------------------------------------------------------
// K1: s_src[n] = h[n,:].(W_fc^T w_src), s_dst[n] = h[n,:].(W_fc^T w_dst)
// One block per row n; thread m owns column m of W_fc.
// ---------------------------------------------------------------------------
__global__ __launch_bounds__(256) void compute_s_kernel(
    const float* __restrict__ h,
    const float* __restrict__ W_fc,
    const float* __restrict__ W_attn,
    float* __restrict__ s_src,
    float* __restrict__ s_dst) {
  const int n = blockIdx.x;
  const int m = threadIdx.x;

  float v_src = 0.f, v_dst = 0.f;
#pragma unroll 8
  for (int k = 0; k < OUT_DIM; ++k) {
    float w = W_fc[k * IN_DIM + m];
    v_src += w * W_attn[k];
    v_dst += w * W_attn[OUT_DIM + k];
  }
  const float hv = h[n * IN_DIM + m];
  float ps = hv * v_src;
  float pd = hv * v_dst;

  for (int off = 32; off > 0; off >>= 1) {
    ps += __shfl_down(ps, off, 64);
    pd += __shfl_down(pd, off, 64);
  }
  __shared__ float sm_s[4], sm_d[4];
  const int wave = m >> 6, lane = m & 63;
  if (lane == 0) { sm_s[wave] = ps; sm_d[wave] = pd; }
  __syncthreads();
  if (m == 0) {
    s_src[n] = sm_s[0] + sm_s[1] + sm_s[2] + sm_s[3];
    s_dst[n] = sm_d[0] + sm_d[1] + sm_d[2] + sm_d[3];
  }
}

// ---------------------------------------------------------------------------
// K2: per-row softmax stats over e[i,j] = lrelu(s_dst[i] + s_src[j]).
// ---------------------------------------------------------------------------
__global__ __launch_bounds__(256) void row_stats_kernel(
    const float* __restrict__ s_src,
    const float* __restrict__ s_dst,
    float* __restrict__ row_max,
    float* __restrict__ row_rdenom) {
  const int i = blockIdx.x;
  const int t = threadIdx.x;
  const float sd = s_dst[i];

  float ev[4];
  float mx = -INFINITY;
#pragma unroll
  for (int r = 0; r < 4; ++r) {
    float e = sd + s_src[t + r * 256];
    e = e > 0.f ? e : NEG_SLOPE * e;
    ev[r] = e;
    mx = fmaxf(mx, e);
  }
  for (int off = 32; off > 0; off >>= 1) mx = fmaxf(mx, __shfl_down(mx, off, 64));

  __shared__ float sm[4];
  __shared__ float s_bcast;
  const int wave = t >> 6, lane = t & 63;
  if (lane == 0) sm[wave] = mx;
  __syncthreads();
  if (t == 0) s_bcast = fmaxf(fmaxf(sm[0], sm[1]), fmaxf(sm[2], sm[3]));
  __syncthreads();
  const float M = s_bcast;

  float sum = 0.f;
#pragma unroll
  for (int r = 0; r < 4; ++r) sum += __expf(ev[r] - M);
  for (int off = 32; off > 0; off >>= 1) sum += __shfl_down(sum, off, 64);

  __shared__ float ss[4];
  if (lane == 0) ss[wave] = sum;
  __syncthreads();
  if (t == 0) {
    row_max[i] = M;
    row_rdenom[i] = 1.0f / (ss[0] + ss[1] + ss[2] + ss[3]);
  }
}

// ---------------------------------------------------------------------------
// K3: streaming blend, row-segment-pinned blocks.
// Block b: row = b / SEGS_PER_ROW, segment = b % SEGS_PER_ROW (128 pairs).
// Prologue: 128 threads each compute one alpha into LDS (1 exp each).
// Inner loop: exactly 3 vmem ops (load a, load q, store o) + 1 broadcast
// ds_read per float4 — removes the 4 per-iteration stats loads that made
// R1 vmem-issue-bound (7 vmem/48B ≈ 191 µs predicted ≈ 186 µs measured).
// ---------------------------------------------------------------------------
__global__ __launch_bounds__(256) void blend_kernel(
    const float4* __restrict__ action,
    const float4* __restrict__ policy,
    const float* __restrict__ s_src,
    const float* __restrict__ s_dst,
    const float* __restrict__ row_max,
    const float* __restrict__ row_rdenom,
    float4* __restrict__ out) {
  const int b = blockIdx.x;
  const int row = b >> 3;            // b / SEGS_PER_ROW
  const int seg = b & 7;             // b % SEGS_PER_ROW
  const int tid = threadIdx.x;

  __shared__ float alpha_lds[SEG_PAIRS];

  if (tid < SEG_PAIRS) {
    const int j = seg * SEG_PAIRS + tid;
    float e = s_dst[row] + s_src[j];     // row-uniform + per-thread
    e = e > 0.f ? e : NEG_SLOPE * e;
    alpha_lds[tid] = __expf(e - row_max[row]) * row_rdenom[row];
  }
  __syncthreads();

  const long base = (long)row * ROW_T4 + seg * SEG_T4;

#pragma unroll
  for (int k = 0; k < ITERS; ++k) {
    const int off = k * 256 + tid;       // 0..2047 within segment
    const float alpha = alpha_lds[off >> 4];
    const float4 a = action[base + off];
    const float4 q = policy[base + off];
    float4 o;
    o.x = alpha * a.x + (1.f - alpha) * q.x;
    o.y = alpha * a.y + (1.f - alpha) * q.y;
    o.z = alpha * a.z + (1.f - alpha) * q.z;
    o.w = alpha * a.w + (1.f - alpha) * q.w;
    out[base + off] = o;
  }
}

extern "C" void kernel_launch(void* const* d_in, const int* in_sizes, int n_in,
                              void* d_out, int out_size, void* d_ws, size_t ws_size,
                              hipStream_t stream) {
  const float* h      = (const float*)d_in[0];
  const float* action = (const float*)d_in[1];
  const float* policy = (const float*)d_in[2];
  const float* W_fc   = (const float*)d_in[3];
  const float* W_attn = (const float*)d_in[4];
  float* out = (float*)d_out;

  float* s_src      = (float*)d_ws;
  float* s_dst      = s_src + NROWS;
  float* row_max    = s_dst + NROWS;
  float* row_rdenom = row_max + NROWS;

  compute_s_kernel<<<NROWS, 256, 0, stream>>>(h, W_fc, W_attn, s_src, s_dst);
  row_stats_kernel<<<NROWS, 256, 0, stream>>>(s_src, s_dst, row_max, row_rdenom);

  blend_kernel<<<NROWS * SEGS_PER_ROW, 256, 0, stream>>>(
      (const float4*)action, (const float4*)policy,
      s_src, s_dst, row_max, row_rdenom,
      (float4*)out);
}